// Round 1
// baseline (613.344 us; speedup 1.0000x reference)
//
#include <hip/hip_runtime.h>
#include <hip/hip_bf16.h>
#include <stdint.h>

typedef unsigned short u16;
typedef __attribute__((ext_vector_type(8))) __bf16 bf16x8;
typedef __attribute__((ext_vector_type(4))) float f32x4;
typedef __attribute__((ext_vector_type(8))) u16 us8;

#define QSCALE 0.08838834764831843f

__device__ __forceinline__ u16 f2bf(float f) {
  unsigned u = __float_as_uint(f);
  u += 0x7fffu + ((u >> 16) & 1u);
  return (u16)(u >> 16);
}
__device__ __forceinline__ float bf2f(u16 h) {
  return __uint_as_float(((unsigned)h) << 16);
}
// async global->LDS, 16B per lane. lds dst must be wave-uniform base (HW adds lane*16).
__device__ __forceinline__ void gload16(const void* g, void* l) {
  __builtin_amdgcn_global_load_lds(
      (const __attribute__((address_space(1))) unsigned int*)g,
      (__attribute__((address_space(3))) unsigned int*)l, 16, 0, 0);
}

// ---------------------------------------------------------------------------
// P1: weight prep. 8 sections (blockIdx.z): transpose f32 [2048][N] -> bf16 [N][2048],
// with optional second source added (Wk/Wv sum over axis 1, in f32).
// ---------------------------------------------------------------------------
__global__ __launch_bounds__(256) void wprep(
    const float* __restrict__ Wq, const float* __restrict__ Wk,
    const float* __restrict__ Wv, const float* __restrict__ Wo,
    u16* __restrict__ WCT, u16* __restrict__ WOT) {
  const int sec = blockIdx.z;
  const float* s0;
  const float* s1 = nullptr;
  u16* dst;
  int N;
  switch (sec) {
    case 0: s0 = Wq;                 dst = WCT;               N = 2048; break;
    case 1: s0 = Wq + 2048*2048;     dst = WCT + 2048*2048;   N = 2048; break;
    case 2: s0 = Wk;                 s1 = Wk + 2048*512;      dst = WCT + 4096*2048; N = 512; break;
    case 3: s0 = Wk + 2*2048*512;    s1 = Wk + 3*2048*512;    dst = WCT + 4608*2048; N = 512; break;
    case 4: s0 = Wv;                 s1 = Wv + 2048*512;      dst = WCT + 5120*2048; N = 512; break;
    case 5: s0 = Wv + 2*2048*512;    s1 = Wv + 3*2048*512;    dst = WCT + 5632*2048; N = 512; break;
    case 6: s0 = Wo;                 dst = WOT;               N = 2048; break;
    default: s0 = Wo + 2048*2048;    dst = WOT + 2048*2048;   N = 2048; break;
  }
  const int n0 = blockIdx.x * 32;
  if (n0 >= N) return;
  const int k0 = blockIdx.y * 32;
  __shared__ float tile[32][33];
  const int tx = threadIdx.x & 31, ty = threadIdx.x >> 5;
#pragma unroll
  for (int i = 0; i < 4; ++i) {
    int k = k0 + ty + 8 * i;
    float v = s0[(size_t)k * N + n0 + tx];
    if (s1) v += s1[(size_t)k * N + n0 + tx];
    tile[ty + 8 * i][tx] = v;
  }
  __syncthreads();
#pragma unroll
  for (int i = 0; i < 4; ++i) {
    int n = n0 + ty + 8 * i;
    dst[(size_t)n * 2048 + k0 + tx] = f2bf(tile[tx][ty + 8 * i]);
  }
}

// ---------------------------------------------------------------------------
// P2: x f32 -> bf16, vectorized (8 elems/thread)
// ---------------------------------------------------------------------------
__global__ __launch_bounds__(256) void xcast(const float* __restrict__ x,
                                             u16* __restrict__ Xbf) {
  size_t base = ((size_t)blockIdx.x * 256 + threadIdx.x) * 8;
  float4 a = *(const float4*)&x[base];
  float4 c = *(const float4*)&x[base + 4];
  us8 o;
  o[0] = f2bf(a.x); o[1] = f2bf(a.y); o[2] = f2bf(a.z); o[3] = f2bf(a.w);
  o[4] = f2bf(c.x); o[5] = f2bf(c.y); o[6] = f2bf(c.z); o[7] = f2bf(c.w);
  *(us8*)&Xbf[base] = o;
}

// ---------------------------------------------------------------------------
// G1: C[M][N] = A[M][K] @ B[N][K]^T, all bf16, f32 acc, bf16 out.
// m97 structure: 128x128 tile, BK=32, 4 waves (2x2 of 64x64), global_load_lds w=16.
// ---------------------------------------------------------------------------
__global__ __launch_bounds__(256) void gemm_bt(
    const u16* __restrict__ A, const u16* __restrict__ B, u16* __restrict__ C,
    int Mdim, int Ndim, int Kdim) {
  __shared__ u16 As[128 * 32];
  __shared__ u16 Bs[128 * 32];
  const int nbx = gridDim.x;
  const int nwg = nbx * gridDim.y;
  int bid = blockIdx.y * nbx + blockIdx.x;
  const int q = nwg >> 3;  // nwg % 8 == 0 for all our launches -> bijective
  int swz = (bid & 7) * q + (bid >> 3);
  const int bx = swz % nbx, by = swz / nbx;
  const int row0 = by * 128, col0 = bx * 128;
  const int tid = threadIdx.x, wid = tid >> 6, lane = tid & 63;
  const int lr = lane & 15, lg = lane >> 4;
  const int wr = wid >> 1, wc = wid & 1;
  const u16* Abase = A + (size_t)row0 * Kdim;
  const u16* Bbase = B + (size_t)col0 * Kdim;

  f32x4 acc[4][4];
#pragma unroll
  for (int m = 0; m < 4; ++m)
#pragma unroll
    for (int n = 0; n < 4; ++n)
#pragma unroll
      for (int r = 0; r < 4; ++r) acc[m][n][r] = 0.f;

  for (int k0 = 0; k0 < Kdim; k0 += 32) {
#pragma unroll
    for (int j = 0; j < 2; ++j) {
      int c = j * 256 + wid * 64 + lane;
      int r = c >> 2, g = c & 3;  // 4 x 16B groups per 32-wide row
      gload16(Abase + (size_t)r * Kdim + k0 + g * 8, &As[(j * 256 + wid * 64) * 8]);
      gload16(Bbase + (size_t)r * Kdim + k0 + g * 8, &Bs[(j * 256 + wid * 64) * 8]);
    }
    __syncthreads();
    bf16x8 af[4], bfr[4];
#pragma unroll
    for (int m = 0; m < 4; ++m)
      af[m] = *(const bf16x8*)&As[(64 * wr + 16 * m + lr) * 32 + 8 * lg];
#pragma unroll
    for (int n = 0; n < 4; ++n)
      bfr[n] = *(const bf16x8*)&Bs[(64 * wc + 16 * n + lr) * 32 + 8 * lg];
#pragma unroll
    for (int m = 0; m < 4; ++m)
#pragma unroll
      for (int n = 0; n < 4; ++n)
        acc[m][n] = __builtin_amdgcn_mfma_f32_16x16x32_bf16(af[m], bfr[n], acc[m][n], 0, 0, 0);
    __syncthreads();
  }
#pragma unroll
  for (int m = 0; m < 4; ++m)
#pragma unroll
    for (int n = 0; n < 4; ++n)
#pragma unroll
      for (int r = 0; r < 4; ++r) {
        int grow = row0 + 64 * wr + 16 * m + 4 * lg + r;
        int gcol = col0 + 64 * wc + 16 * n + lr;
        C[(size_t)grow * Ndim + gcol] = f2bf(acc[m][n][r]);
      }
}

// ---------------------------------------------------------------------------
// G2: O-projection gemm (M=4096,N=4096,K=2048) with fused modality-select f32 store.
// cols [0,2048) = modality 0, [2048,4096) = modality 1.
// ---------------------------------------------------------------------------
__global__ __launch_bounds__(256) void gemm_out(
    const u16* __restrict__ A, const u16* __restrict__ B,
    const int* __restrict__ mid, float* __restrict__ out) {
  __shared__ u16 As[128 * 32];
  __shared__ u16 Bs[128 * 32];
  const int nbx = gridDim.x;              // 32
  const int nwg = nbx * gridDim.y;        // 1024
  int bid = blockIdx.y * nbx + blockIdx.x;
  const int q = nwg >> 3;
  int swz = (bid & 7) * q + (bid >> 3);
  const int bx = swz % nbx, by = swz / nbx;
  const int row0 = by * 128, col0 = bx * 128;
  const int tid = threadIdx.x, wid = tid >> 6, lane = tid & 63;
  const int lr = lane & 15, lg = lane >> 4;
  const int wr = wid >> 1, wc = wid & 1;
  const u16* Abase = A + (size_t)row0 * 2048;
  const u16* Bbase = B + (size_t)col0 * 2048;

  f32x4 acc[4][4];
#pragma unroll
  for (int m = 0; m < 4; ++m)
#pragma unroll
    for (int n = 0; n < 4; ++n)
#pragma unroll
      for (int r = 0; r < 4; ++r) acc[m][n][r] = 0.f;

  for (int k0 = 0; k0 < 2048; k0 += 32) {
#pragma unroll
    for (int j = 0; j < 2; ++j) {
      int c = j * 256 + wid * 64 + lane;
      int r = c >> 2, g = c & 3;
      gload16(Abase + (size_t)r * 2048 + k0 + g * 8, &As[(j * 256 + wid * 64) * 8]);
      gload16(Bbase + (size_t)r * 2048 + k0 + g * 8, &Bs[(j * 256 + wid * 64) * 8]);
    }
    __syncthreads();
    bf16x8 af[4], bfr[4];
#pragma unroll
    for (int m = 0; m < 4; ++m)
      af[m] = *(const bf16x8*)&As[(64 * wr + 16 * m + lr) * 32 + 8 * lg];
#pragma unroll
    for (int n = 0; n < 4; ++n)
      bfr[n] = *(const bf16x8*)&Bs[(64 * wc + 16 * n + lr) * 32 + 8 * lg];
#pragma unroll
    for (int m = 0; m < 4; ++m)
#pragma unroll
      for (int n = 0; n < 4; ++n)
        acc[m][n] = __builtin_amdgcn_mfma_f32_16x16x32_bf16(af[m], bfr[n], acc[m][n], 0, 0, 0);
    __syncthreads();
  }
#pragma unroll
  for (int m = 0; m < 4; ++m)
#pragma unroll
    for (int n = 0; n < 4; ++n)
#pragma unroll
      for (int r = 0; r < 4; ++r) {
        int grow = row0 + 64 * wr + 16 * m + 4 * lg + r;
        int gcol = col0 + 64 * wc + 16 * n + lr;
        int mod = gcol >> 11;
        if (mid[grow] == mod)
          out[(size_t)grow * 2048 + (gcol & 2047)] = acc[m][n][r];
      }
}

// ---------------------------------------------------------------------------
// A0: modality select + RoPE for Q (scaled by 1/sqrt(128)) and K.
// One block per token. Qr: [b][h][s][128], Kr: [b][kv][s][128], bf16.
// RoPE matrix read directly from freq_cis input: out0 = x0*F0 + x1*F2; out1 = x0*F1 + x1*F3.
// ---------------------------------------------------------------------------
__global__ __launch_bounds__(256) void rope_select(
    const u16* __restrict__ QKV, const int* __restrict__ mid,
    const float* __restrict__ fc, u16* __restrict__ Qr, u16* __restrict__ Kr) {
  const int t = blockIdx.x;
  const int b = t >> 11, s = t & 2047;
  const int m = mid[t];
  __shared__ float Fs[256];
  Fs[threadIdx.x] = fc[(size_t)s * 256 + threadIdx.x];
  __syncthreads();
  const int tid = threadIdx.x;
  {  // Q: 1024 pairs, 4/thread
    int p0 = tid * 4;
    int h = p0 >> 6, ph0 = p0 & 63;
    const u16* src = QKV + (size_t)t * 6144 + m * 2048 + h * 128 + 2 * ph0;
    us8 v = *(const us8*)src;
    us8 o;
#pragma unroll
    for (int j = 0; j < 4; ++j) {
      float x0 = bf2f(v[2 * j]), x1 = bf2f(v[2 * j + 1]);
      const float* F = &Fs[(ph0 + j) * 4];
      o[2 * j]     = f2bf((x0 * F[0] + x1 * F[2]) * QSCALE);
      o[2 * j + 1] = f2bf((x0 * F[1] + x1 * F[3]) * QSCALE);
    }
    *(us8*)(Qr + (((size_t)(b * 16 + h) * 2048) + s) * 128 + 2 * ph0) = o;
  }
  if (tid < 64) {  // K: 256 pairs, 4/thread
    int p0 = tid * 4;
    int kh = p0 >> 6, ph0 = p0 & 63;
    const u16* src = QKV + (size_t)t * 6144 + 4096 + m * 512 + kh * 128 + 2 * ph0;
    us8 v = *(const us8*)src;
    us8 o;
#pragma unroll
    for (int j = 0; j < 4; ++j) {
      float x0 = bf2f(v[2 * j]), x1 = bf2f(v[2 * j + 1]);
      const float* F = &Fs[(ph0 + j) * 4];
      o[2 * j]     = f2bf(x0 * F[0] + x1 * F[2]);
      o[2 * j + 1] = f2bf(x0 * F[1] + x1 * F[3]);
    }
    *(us8*)(Kr + (((size_t)(b * 4 + kh) * 2048) + s) * 128 + 2 * ph0) = o;
  }
}

// ---------------------------------------------------------------------------
// A1: V select + transpose -> Vt [b][kv][d][s] bf16 (so PV B-frags are contiguous in s)
// ---------------------------------------------------------------------------
__global__ __launch_bounds__(256) void vtrans(
    const u16* __restrict__ QKV, const int* __restrict__ mid, u16* __restrict__ Vt) {
  __shared__ u16 tilebuf[32][34];
  const int s0 = blockIdx.x * 32, d0 = blockIdx.y * 32, b = blockIdx.z;
  const int tx = threadIdx.x & 31, ty = threadIdx.x >> 5;
#pragma unroll
  for (int i = 0; i < 4; ++i) {
    int s = s0 + ty + 8 * i;
    int t = b * 2048 + s;
    int m = mid[t];
    tilebuf[ty + 8 * i][tx] = QKV[(size_t)t * 6144 + 5120 + m * 512 + d0 + tx];
  }
  __syncthreads();
#pragma unroll
  for (int i = 0; i < 4; ++i) {
    int d = d0 + ty + 8 * i;
    Vt[(((size_t)(b * 4 + (d >> 7)) * 128) + (d & 127)) * 2048 + s0 + tx] =
        tilebuf[tx][ty + 8 * i];
  }
}

// ---------------------------------------------------------------------------
// A2: non-causal flash attention. grid (32 qtiles, 16 heads, 2 b), 4 waves x 16 qrows.
// K/V staged 64-key tiles via global_load_lds with XOR swizzle done on the SOURCE side
// (linear LDS dest), reads apply the same XOR -> bank-conflict-free ds_read_b128.
// ---------------------------------------------------------------------------
__global__ __launch_bounds__(256) void attn(
    const u16* __restrict__ Qr, const u16* __restrict__ Kr,
    const u16* __restrict__ Vt, u16* __restrict__ AO) {
  __shared__ u16 Ks[64 * 128];   // [key][d], swizzled 16B groups
  __shared__ u16 Vs[128 * 64];   // [d][key], swizzled
  __shared__ u16 Ps[4][16 * 64]; // per-wave P, swizzled
  const int qb = blockIdx.x, h = blockIdx.y, b = blockIdx.z;
  const int kvh = h >> 2;
  const int tid = threadIdx.x, wid = tid >> 6, lane = tid & 63;
  const int lr = lane & 15, lg = lane >> 4;
  const u16* qp = Qr + (((size_t)(b * 16 + h) * 2048) + qb * 64 + 16 * wid) * 128;
  const u16* kp = Kr + ((size_t)(b * 4 + kvh) * 2048) * 128;
  const u16* vp = Vt + ((size_t)(b * 4 + kvh) * 128) * 2048;

  bf16x8 qf[4];
#pragma unroll
  for (int t4 = 0; t4 < 4; ++t4)
    qf[t4] = *(const bf16x8*)(qp + (size_t)lr * 128 + 32 * t4 + 8 * lg);

  f32x4 o[8];
#pragma unroll
  for (int i = 0; i < 8; ++i)
#pragma unroll
    for (int r = 0; r < 4; ++r) o[i][r] = 0.f;
  float mrow[4] = {-1e30f, -1e30f, -1e30f, -1e30f};
  float lrow[4] = {0.f, 0.f, 0.f, 0.f};

  for (int kb = 0; kb < 2048; kb += 64) {
#pragma unroll
    for (int j = 0; j < 4; ++j) {
      int c = j * 256 + wid * 64 + lane;
      int rk = c >> 4, gk = (c & 15) ^ (rk & 7);   // K: 16 groups/row
      gload16(kp + (size_t)(kb + rk) * 128 + gk * 8, &Ks[(j * 256 + wid * 64) * 8]);
      int rv = c >> 3, gv = (c & 7) ^ (rv & 7);    // V: 8 groups/row
      gload16(vp + (size_t)rv * 2048 + kb + gv * 8, &Vs[(j * 256 + wid * 64) * 8]);
    }
    __syncthreads();

    f32x4 s[4];
#pragma unroll
    for (int nf = 0; nf < 4; ++nf)
#pragma unroll
      for (int r = 0; r < 4; ++r) s[nf][r] = 0.f;
#pragma unroll
    for (int nf = 0; nf < 4; ++nf) {
      int R = 16 * nf + lr;
#pragma unroll
      for (int t4 = 0; t4 < 4; ++t4) {
        bf16x8 kf = *(const bf16x8*)&Ks[R * 128 + (((4 * t4 + lg) ^ (R & 7)) * 8)];
        s[nf] = __builtin_amdgcn_mfma_f32_16x16x32_bf16(qf[t4], kf, s[nf], 0, 0, 0);
      }
    }
    // online softmax; lane holds rows 4*lg+r, cols 16*nf+lr
    float sc[4];
#pragma unroll
    for (int r = 0; r < 4; ++r) {
      float mx = fmaxf(fmaxf(s[0][r], s[1][r]), fmaxf(s[2][r], s[3][r]));
      mx = fmaxf(mx, __shfl_xor(mx, 1));
      mx = fmaxf(mx, __shfl_xor(mx, 2));
      mx = fmaxf(mx, __shfl_xor(mx, 4));
      mx = fmaxf(mx, __shfl_xor(mx, 8));
      float mn = fmaxf(mrow[r], mx);
      sc[r] = __expf(mrow[r] - mn);
      float ps = 0.f;
#pragma unroll
      for (int nf = 0; nf < 4; ++nf) {
        float e = __expf(s[nf][r] - mn);
        s[nf][r] = e;
        ps += e;
      }
      ps += __shfl_xor(ps, 1);
      ps += __shfl_xor(ps, 2);
      ps += __shfl_xor(ps, 4);
      ps += __shfl_xor(ps, 8);
      lrow[r] = lrow[r] * sc[r] + ps;
      mrow[r] = mn;
    }
#pragma unroll
    for (int i = 0; i < 8; ++i)
#pragma unroll
      for (int r = 0; r < 4; ++r) o[i][r] *= sc[r];
    // P -> per-wave LDS (bf16, swizzled), then read back as A-fragments
    u16* pw = Ps[wid];
#pragma unroll
    for (int nf = 0; nf < 4; ++nf) {
      int cg = 2 * nf + (lr >> 3), ci = lr & 7;
#pragma unroll
      for (int r = 0; r < 4; ++r) {
        int prow = 4 * lg + r;
        pw[prow * 64 + ((cg ^ (prow & 7)) * 8) + ci] = f2bf(s[nf][r]);
      }
    }
#pragma unroll
    for (int ks = 0; ks < 2; ++ks) {
      bf16x8 pa = *(const bf16x8*)&pw[lr * 64 + (((4 * ks + lg) ^ (lr & 7)) * 8)];
#pragma unroll
      for (int n2 = 0; n2 < 8; ++n2) {
        int R2 = 16 * n2 + lr;
        bf16x8 vf = *(const bf16x8*)&Vs[R2 * 64 + (((4 * ks + lg) ^ (R2 & 7)) * 8)];
        o[n2] = __builtin_amdgcn_mfma_f32_16x16x32_bf16(pa, vf, o[n2], 0, 0, 0);
      }
    }
    __syncthreads();
  }
#pragma unroll
  for (int n2 = 0; n2 < 8; ++n2)
#pragma unroll
    for (int r = 0; r < 4; ++r) {
      int qrow = qb * 64 + 16 * wid + 4 * lg + r;
      AO[((size_t)(b * 2048) + qrow) * 2048 + h * 128 + 16 * n2 + lr] =
          f2bf(o[n2][r] / lrow[r]);
    }
}

// ---------------------------------------------------------------------------
extern "C" void kernel_launch(void* const* d_in, const int* in_sizes, int n_in,
                              void* d_out, int out_size, void* d_ws, size_t ws_size,
                              hipStream_t stream) {
  const float* x  = (const float*)d_in[0];
  const float* fc = (const float*)d_in[1];
  const float* Wq = (const float*)d_in[2];
  const float* Wk = (const float*)d_in[3];
  const float* Wv = (const float*)d_in[4];
  const float* Wo = (const float*)d_in[5];
  const int* mid  = (const int*)d_in[6];
  float* out = (float*)d_out;
  char* ws = (char*)d_ws;

  // ws layout (bytes)
  u16* XBF = (u16*)(ws);                 // 4096x2048 bf16        16.8MB
  u16* WCT = (u16*)(ws + 16777216);      // 6144x2048 bf16        25.2MB
  u16* WOT = (u16*)(ws + 41943040);      // 4096x2048 bf16        16.8MB
  u16* QKV = (u16*)(ws + 58720256);      // 4096x6144 bf16        50.3MB
  u16* QR  = (u16*)(ws + 109051904);     // [2][16][2048][128]    16.8MB
  u16* KR  = (u16*)(ws + 125829120);     // [2][4][2048][128]      4.2MB
  u16* VT  = (u16*)(ws + 130023424);     // [2][4][128][2048]      4.2MB
  u16* AO  = (u16*)(ws + 134217728);     // [4096][2048]          16.8MB
  if (ws_size < 150994944) return;       // loud failure if scratch too small

  wprep<<<dim3(64, 64, 8), dim3(256), 0, stream>>>(Wq, Wk, Wv, Wo, WCT, WOT);
  xcast<<<dim3(4096), dim3(256), 0, stream>>>(x, XBF);
  gemm_bt<<<dim3(48, 32), dim3(256), 0, stream>>>(XBF, WCT, QKV, 4096, 6144, 2048);
  rope_select<<<dim3(4096), dim3(256), 0, stream>>>(QKV, mid, fc, QR, KR);
  vtrans<<<dim3(64, 16, 2), dim3(256), 0, stream>>>(QKV, mid, VT);
  attn<<<dim3(32, 16, 2), dim3(256), 0, stream>>>(QR, KR, VT, AO);
  gemm_out<<<dim3(32, 32), dim3(256), 0, stream>>>(AO, WOT, mid, out);
}

// Round 2
// 539.981 us; speedup vs baseline: 1.1359x; 1.1359x over previous
//
#include <hip/hip_runtime.h>
#include <hip/hip_bf16.h>
#include <stdint.h>

typedef unsigned short u16;
typedef __attribute__((ext_vector_type(8))) __bf16 bf16x8;
typedef __attribute__((ext_vector_type(4))) float f32x4;
typedef __attribute__((ext_vector_type(16))) float f32x16;
typedef __attribute__((ext_vector_type(8))) u16 us8;
typedef __attribute__((ext_vector_type(4))) unsigned u32x4;

#define QSCALE 0.08838834764831843f

__device__ __forceinline__ u16 f2bf(float f) {
  unsigned u = __float_as_uint(f);
  u += 0x7fffu + ((u >> 16) & 1u);
  return (u16)(u >> 16);
}
__device__ __forceinline__ float bf2f(u16 h) {
  return __uint_as_float(((unsigned)h) << 16);
}
// async global->LDS, 16B per lane. lds dst must be wave-uniform base (HW adds lane*16).
__device__ __forceinline__ void gload16(const void* g, void* l) {
  __builtin_amdgcn_global_load_lds(
      (const __attribute__((address_space(1))) unsigned int*)g,
      (__attribute__((address_space(3))) unsigned int*)l, 16, 0, 0);
}
__device__ __forceinline__ unsigned sx32(unsigned v) {
  return (unsigned)__shfl_xor((int)v, 32, 64);
}

// ---------------------------------------------------------------------------
// P1: weight prep. 8 sections (blockIdx.z): transpose f32 [2048][N] -> bf16 [N][2048],
// with optional second source added (Wk/Wv sum over axis 1, in f32).
// ---------------------------------------------------------------------------
__global__ __launch_bounds__(256) void wprep(
    const float* __restrict__ Wq, const float* __restrict__ Wk,
    const float* __restrict__ Wv, const float* __restrict__ Wo,
    u16* __restrict__ WCT, u16* __restrict__ WOT) {
  const int sec = blockIdx.z;
  const float* s0;
  const float* s1 = nullptr;
  u16* dst;
  int N;
  switch (sec) {
    case 0: s0 = Wq;                 dst = WCT;               N = 2048; break;
    case 1: s0 = Wq + 2048*2048;     dst = WCT + 2048*2048;   N = 2048; break;
    case 2: s0 = Wk;                 s1 = Wk + 2048*512;      dst = WCT + 4096*2048; N = 512; break;
    case 3: s0 = Wk + 2*2048*512;    s1 = Wk + 3*2048*512;    dst = WCT + 4608*2048; N = 512; break;
    case 4: s0 = Wv;                 s1 = Wv + 2048*512;      dst = WCT + 5120*2048; N = 512; break;
    case 5: s0 = Wv + 2*2048*512;    s1 = Wv + 3*2048*512;    dst = WCT + 5632*2048; N = 512; break;
    case 6: s0 = Wo;                 dst = WOT;               N = 2048; break;
    default: s0 = Wo + 2048*2048;    dst = WOT + 2048*2048;   N = 2048; break;
  }
  const int n0 = blockIdx.x * 32;
  if (n0 >= N) return;
  const int k0 = blockIdx.y * 32;
  __shared__ float tile[32][33];
  const int tx = threadIdx.x & 31, ty = threadIdx.x >> 5;
#pragma unroll
  for (int i = 0; i < 4; ++i) {
    int k = k0 + ty + 8 * i;
    float v = s0[(size_t)k * N + n0 + tx];
    if (s1) v += s1[(size_t)k * N + n0 + tx];
    tile[ty + 8 * i][tx] = v;
  }
  __syncthreads();
#pragma unroll
  for (int i = 0; i < 4; ++i) {
    int n = n0 + ty + 8 * i;
    dst[(size_t)n * 2048 + k0 + tx] = f2bf(tile[tx][ty + 8 * i]);
  }
}

// ---------------------------------------------------------------------------
// P2: x f32 -> bf16, vectorized (8 elems/thread)
// ---------------------------------------------------------------------------
__global__ __launch_bounds__(256) void xcast(const float* __restrict__ x,
                                             u16* __restrict__ Xbf) {
  size_t base = ((size_t)blockIdx.x * 256 + threadIdx.x) * 8;
  float4 a = *(const float4*)&x[base];
  float4 c = *(const float4*)&x[base + 4];
  us8 o;
  o[0] = f2bf(a.x); o[1] = f2bf(a.y); o[2] = f2bf(a.z); o[3] = f2bf(a.w);
  o[4] = f2bf(c.x); o[5] = f2bf(c.y); o[6] = f2bf(c.z); o[7] = f2bf(c.w);
  *(us8*)&Xbf[base] = o;
}

// ---------------------------------------------------------------------------
// G1: C[M][N] = A[M][K] @ B[N][K]^T, all bf16, f32 acc, bf16 out.
// m97 structure: 128x128 tile, BK=32, 4 waves (2x2 of 64x64), global_load_lds w=16.
// ---------------------------------------------------------------------------
__global__ __launch_bounds__(256) void gemm_bt(
    const u16* __restrict__ A, const u16* __restrict__ B, u16* __restrict__ C,
    int Mdim, int Ndim, int Kdim) {
  __shared__ u16 As[128 * 32];
  __shared__ u16 Bs[128 * 32];
  const int nbx = gridDim.x;
  const int nwg = nbx * gridDim.y;
  int bid = blockIdx.y * nbx + blockIdx.x;
  const int q = nwg >> 3;  // nwg % 8 == 0 for all our launches -> bijective
  int swz = (bid & 7) * q + (bid >> 3);
  const int bx = swz % nbx, by = swz / nbx;
  const int row0 = by * 128, col0 = bx * 128;
  const int tid = threadIdx.x, wid = tid >> 6, lane = tid & 63;
  const int lr = lane & 15, lg = lane >> 4;
  const int wr = wid >> 1, wc = wid & 1;
  const u16* Abase = A + (size_t)row0 * Kdim;
  const u16* Bbase = B + (size_t)col0 * Kdim;

  f32x4 acc[4][4];
#pragma unroll
  for (int m = 0; m < 4; ++m)
#pragma unroll
    for (int n = 0; n < 4; ++n)
#pragma unroll
      for (int r = 0; r < 4; ++r) acc[m][n][r] = 0.f;

  for (int k0 = 0; k0 < Kdim; k0 += 32) {
#pragma unroll
    for (int j = 0; j < 2; ++j) {
      int c = j * 256 + wid * 64 + lane;
      int r = c >> 2, g = c & 3;  // 4 x 16B groups per 32-wide row
      gload16(Abase + (size_t)r * Kdim + k0 + g * 8, &As[(j * 256 + wid * 64) * 8]);
      gload16(Bbase + (size_t)r * Kdim + k0 + g * 8, &Bs[(j * 256 + wid * 64) * 8]);
    }
    __syncthreads();
    bf16x8 af[4], bfr[4];
#pragma unroll
    for (int m = 0; m < 4; ++m)
      af[m] = *(const bf16x8*)&As[(64 * wr + 16 * m + lr) * 32 + 8 * lg];
#pragma unroll
    for (int n = 0; n < 4; ++n)
      bfr[n] = *(const bf16x8*)&Bs[(64 * wc + 16 * n + lr) * 32 + 8 * lg];
#pragma unroll
    for (int m = 0; m < 4; ++m)
#pragma unroll
      for (int n = 0; n < 4; ++n)
        acc[m][n] = __builtin_amdgcn_mfma_f32_16x16x32_bf16(af[m], bfr[n], acc[m][n], 0, 0, 0);
    __syncthreads();
  }
#pragma unroll
  for (int m = 0; m < 4; ++m)
#pragma unroll
    for (int n = 0; n < 4; ++n)
#pragma unroll
      for (int r = 0; r < 4; ++r) {
        int grow = row0 + 64 * wr + 16 * m + 4 * lg + r;
        int gcol = col0 + 64 * wc + 16 * n + lr;
        C[(size_t)grow * Ndim + gcol] = f2bf(acc[m][n][r]);
      }
}

// ---------------------------------------------------------------------------
// G2: O-projection gemm (M=4096,N=4096,K=2048) with fused modality-select f32 store.
// cols [0,2048) = modality 0, [2048,4096) = modality 1.
// ---------------------------------------------------------------------------
__global__ __launch_bounds__(256) void gemm_out(
    const u16* __restrict__ A, const u16* __restrict__ B,
    const int* __restrict__ mid, float* __restrict__ out) {
  __shared__ u16 As[128 * 32];
  __shared__ u16 Bs[128 * 32];
  const int nbx = gridDim.x;              // 32
  const int nwg = nbx * gridDim.y;        // 1024
  int bid = blockIdx.y * nbx + blockIdx.x;
  const int q = nwg >> 3;
  int swz = (bid & 7) * q + (bid >> 3);
  const int bx = swz % nbx, by = swz / nbx;
  const int row0 = by * 128, col0 = bx * 128;
  const int tid = threadIdx.x, wid = tid >> 6, lane = tid & 63;
  const int lr = lane & 15, lg = lane >> 4;
  const int wr = wid >> 1, wc = wid & 1;
  const u16* Abase = A + (size_t)row0 * 2048;
  const u16* Bbase = B + (size_t)col0 * 2048;

  f32x4 acc[4][4];
#pragma unroll
  for (int m = 0; m < 4; ++m)
#pragma unroll
    for (int n = 0; n < 4; ++n)
#pragma unroll
      for (int r = 0; r < 4; ++r) acc[m][n][r] = 0.f;

  for (int k0 = 0; k0 < 2048; k0 += 32) {
#pragma unroll
    for (int j = 0; j < 2; ++j) {
      int c = j * 256 + wid * 64 + lane;
      int r = c >> 2, g = c & 3;
      gload16(Abase + (size_t)r * 2048 + k0 + g * 8, &As[(j * 256 + wid * 64) * 8]);
      gload16(Bbase + (size_t)r * 2048 + k0 + g * 8, &Bs[(j * 256 + wid * 64) * 8]);
    }
    __syncthreads();
    bf16x8 af[4], bfr[4];
#pragma unroll
    for (int m = 0; m < 4; ++m)
      af[m] = *(const bf16x8*)&As[(64 * wr + 16 * m + lr) * 32 + 8 * lg];
#pragma unroll
    for (int n = 0; n < 4; ++n)
      bfr[n] = *(const bf16x8*)&Bs[(64 * wc + 16 * n + lr) * 32 + 8 * lg];
#pragma unroll
    for (int m = 0; m < 4; ++m)
#pragma unroll
      for (int n = 0; n < 4; ++n)
        acc[m][n] = __builtin_amdgcn_mfma_f32_16x16x32_bf16(af[m], bfr[n], acc[m][n], 0, 0, 0);
    __syncthreads();
  }
#pragma unroll
  for (int m = 0; m < 4; ++m)
#pragma unroll
    for (int n = 0; n < 4; ++n)
#pragma unroll
      for (int r = 0; r < 4; ++r) {
        int grow = row0 + 64 * wr + 16 * m + 4 * lg + r;
        int gcol = col0 + 64 * wc + 16 * n + lr;
        int mod = gcol >> 11;
        if (mid[grow] == mod)
          out[(size_t)grow * 2048 + (gcol & 2047)] = acc[m][n][r];
      }
}

// ---------------------------------------------------------------------------
// A0: modality select + RoPE for Q (scaled by 1/sqrt(128)) and K.
// ---------------------------------------------------------------------------
__global__ __launch_bounds__(256) void rope_select(
    const u16* __restrict__ QKV, const int* __restrict__ mid,
    const float* __restrict__ fc, u16* __restrict__ Qr, u16* __restrict__ Kr) {
  const int t = blockIdx.x;
  const int b = t >> 11, s = t & 2047;
  const int m = mid[t];
  __shared__ float Fs[256];
  Fs[threadIdx.x] = fc[(size_t)s * 256 + threadIdx.x];
  __syncthreads();
  const int tid = threadIdx.x;
  {  // Q: 1024 pairs, 4/thread
    int p0 = tid * 4;
    int h = p0 >> 6, ph0 = p0 & 63;
    const u16* src = QKV + (size_t)t * 6144 + m * 2048 + h * 128 + 2 * ph0;
    us8 v = *(const us8*)src;
    us8 o;
#pragma unroll
    for (int j = 0; j < 4; ++j) {
      float x0 = bf2f(v[2 * j]), x1 = bf2f(v[2 * j + 1]);
      const float* F = &Fs[(ph0 + j) * 4];
      o[2 * j]     = f2bf((x0 * F[0] + x1 * F[2]) * QSCALE);
      o[2 * j + 1] = f2bf((x0 * F[1] + x1 * F[3]) * QSCALE);
    }
    *(us8*)(Qr + (((size_t)(b * 16 + h) * 2048) + s) * 128 + 2 * ph0) = o;
  }
  if (tid < 64) {  // K: 256 pairs, 4/thread
    int p0 = tid * 4;
    int kh = p0 >> 6, ph0 = p0 & 63;
    const u16* src = QKV + (size_t)t * 6144 + 4096 + m * 512 + kh * 128 + 2 * ph0;
    us8 v = *(const us8*)src;
    us8 o;
#pragma unroll
    for (int j = 0; j < 4; ++j) {
      float x0 = bf2f(v[2 * j]), x1 = bf2f(v[2 * j + 1]);
      const float* F = &Fs[(ph0 + j) * 4];
      o[2 * j]     = f2bf(x0 * F[0] + x1 * F[2]);
      o[2 * j + 1] = f2bf(x0 * F[1] + x1 * F[3]);
    }
    *(us8*)(Kr + (((size_t)(b * 4 + kh) * 2048) + s) * 128 + 2 * ph0) = o;
  }
}

// ---------------------------------------------------------------------------
// A1: V select + transpose -> Vt [b][kv][d][s] bf16
// ---------------------------------------------------------------------------
__global__ __launch_bounds__(256) void vtrans(
    const u16* __restrict__ QKV, const int* __restrict__ mid, u16* __restrict__ Vt) {
  __shared__ u16 tilebuf[32][34];
  const int s0 = blockIdx.x * 32, d0 = blockIdx.y * 32, b = blockIdx.z;
  const int tx = threadIdx.x & 31, ty = threadIdx.x >> 5;
#pragma unroll
  for (int i = 0; i < 4; ++i) {
    int s = s0 + ty + 8 * i;
    int t = b * 2048 + s;
    int m = mid[t];
    tilebuf[ty + 8 * i][tx] = QKV[(size_t)t * 6144 + 5120 + m * 512 + d0 + tx];
  }
  __syncthreads();
#pragma unroll
  for (int i = 0; i < 4; ++i) {
    int d = d0 + ty + 8 * i;
    Vt[(((size_t)(b * 4 + (d >> 7)) * 128) + (d & 127)) * 2048 + s0 + tx] =
        tilebuf[tx][ty + 8 * i];
  }
}

// ---------------------------------------------------------------------------
// A2: flash attention, 8 waves x 32 q-rows (256-q tile), 32x32x16 MFMA.
// Swapped QK^T: S^T = mfma(K, Q) so q = lane&31 (softmax lane-local).
// PV computes O^T = mfma(V^T, P^T) so q stays lane-local (rescale trivial).
// K/V double-buffered in LDS, stage-early + 1 barrier/tile, XOR-swizzled b128.
// ---------------------------------------------------------------------------
__global__ __launch_bounds__(512, 2) void attn(
    const u16* __restrict__ Qr, const u16* __restrict__ Kr,
    const u16* __restrict__ Vt, u16* __restrict__ AO) {
  __shared__ u16 smem[34816];  // 69632 B: loop = 2 x (16KB K + 16KB V); epilogue = Os[256][136]
  u16* Kbuf[2] = { smem,          smem + 16384 };
  u16* Vbuf[2] = { smem +  8192,  smem + 24576 };
  // carve: [K0 16KB][V0 16KB][K1 16KB][V1 16KB] in u16 units (8192 each)
  Kbuf[0] = smem;          Vbuf[0] = smem + 8192;
  Kbuf[1] = smem + 16384;  Vbuf[1] = smem + 24576;

  const int qt = blockIdx.x, hd = blockIdx.y, b = blockIdx.z;
  const int kvh = hd >> 2;
  const int tid = threadIdx.x, wid = tid >> 6;
  const int l31 = tid & 31, h = (tid >> 5) & 1;
  const bool hi = h != 0;

  const u16* qp = Qr + (((size_t)(b * 16 + hd) * 2048) + qt * 256 + wid * 32 + l31) * 128;
  const u16* kp = Kr + ((size_t)(b * 4 + kvh) * 2048) * 128;
  const u16* vp = Vt + ((size_t)(b * 4 + kvh) * 128) * 2048;

  // Q B-frags: qf[ds] = Q[q = l31][d = 16*ds + 8*h .. +8)
  bf16x8 qf[8];
#pragma unroll
  for (int ds = 0; ds < 8; ++ds)
    qf[ds] = *(const bf16x8*)(qp + 16 * ds + 8 * h);

  f32x16 oacc[4];
#pragma unroll
  for (int dt = 0; dt < 4; ++dt)
#pragma unroll
    for (int r = 0; r < 16; ++r) oacc[dt][r] = 0.f;
  float mrun = -1e30f, lrun = 0.f;

  // ---- stage(kb): K [64 keys][16 slots of 8 d], V [128 d][8 slots of 8 keys]
  // linear LDS dest; XOR swizzle applied on the global source side.
#define STAGE_KV(KB, DK, DV)                                                   \
  {                                                                            \
    _Pragma("unroll") for (int j = 0; j < 2; ++j) {                            \
      int c = j * 512 + tid;                                                   \
      int rk = c >> 4, gk = (c & 15) ^ (rk & 7);                               \
      gload16(kp + (size_t)((KB) + rk) * 128 + gk * 8,                         \
              (DK) + (j * 512 + wid * 64) * 8);                                \
      int rv = c >> 3, gv = (c & 7) ^ (rv & 7);                                \
      gload16(vp + (size_t)rv * 2048 + (KB) + gv * 8,                          \
              (DV) + (j * 512 + wid * 64) * 8);                                \
    }                                                                          \
  }

  STAGE_KV(0, Kbuf[0], Vbuf[0]);
  __syncthreads();

  int cur = 0;
  for (int kb = 0; kb < 2048; kb += 64) {
    const u16* Kb = Kbuf[cur];
    const u16* Vb = Vbuf[cur];
    if (kb + 64 < 2048) STAGE_KV(kb + 64, Kbuf[cur ^ 1], Vbuf[cur ^ 1]);

    // ---- QK^T (swapped): S^T[key][q], acc s0 = keys 0-31, s1 = keys 32-63
    f32x16 s0, s1;
#pragma unroll
    for (int r = 0; r < 16; ++r) { s0[r] = 0.f; s1[r] = 0.f; }
    const int key0 = l31, key1 = 32 + l31;
#pragma unroll
    for (int ds = 0; ds < 8; ++ds) {
      bf16x8 kf0 = *(const bf16x8*)&Kb[key0 * 128 + (((2 * ds + h) ^ (key0 & 7)) * 8)];
      s0 = __builtin_amdgcn_mfma_f32_32x32x16_bf16(kf0, qf[ds], s0, 0, 0, 0);
      bf16x8 kf1 = *(const bf16x8*)&Kb[key1 * 128 + (((2 * ds + h) ^ (key1 & 7)) * 8)];
      s1 = __builtin_amdgcn_mfma_f32_32x32x16_bf16(kf1, qf[ds], s1, 0, 0, 0);
    }

    // ---- online softmax (q = l31; lanes l and l+32 hold disjoint key halves)
    float pm = -1e30f;
#pragma unroll
    for (int r = 0; r < 16; ++r) pm = fmaxf(pm, fmaxf(s0[r], s1[r]));
    pm = fmaxf(pm, __shfl_xor(pm, 32, 64));
    if (!__all(pm <= mrun + 8.f)) {  // defer-max (T13)
      float mn = fmaxf(mrun, pm);
      float sc = __expf(mrun - mn);
      mrun = mn;
      lrun *= sc;
#pragma unroll
      for (int dt = 0; dt < 4; ++dt)
#pragma unroll
        for (int r = 0; r < 16; ++r) oacc[dt][r] *= sc;
    }
    float ls = 0.f;
#pragma unroll
    for (int r = 0; r < 16; ++r) { s0[r] = __expf(s0[r] - mrun); ls += s0[r]; }
#pragma unroll
    for (int r = 0; r < 16; ++r) { s1[r] = __expf(s1[r] - mrun); ls += s1[r]; }
    ls += __shfl_xor(ls, 32, 64);
    lrun += ls;

    // ---- P -> bf16 pairs; redistribute key-halves across lane halves.
    // c[j] holds keys (Kj + 4h, +1); Kj = 8*(j>>1) + 2*(j&1) (+32 for j>=8)
    unsigned c[16];
#pragma unroll
    for (int j = 0; j < 8; ++j) {
      asm("v_cvt_pk_bf16_f32 %0, %1, %2" : "=v"(c[j]) : "v"(s0[2 * j]), "v"(s0[2 * j + 1]));
      asm("v_cvt_pk_bf16_f32 %0, %1, %2" : "=v"(c[8 + j]) : "v"(s1[2 * j]), "v"(s1[2 * j + 1]));
    }

    // ---- PV: O^T[d][q] += V^T[d][k] P^T[k][q]; A = V^T from LDS, B = pa in-reg
#pragma unroll
    for (int st = 0; st < 4; ++st) {
      unsigned w0 = sx32(c[4 * st + 0]);
      unsigned w1 = sx32(c[4 * st + 1]);
      unsigned w2 = sx32(c[4 * st + 2]);
      unsigned w3 = sx32(c[4 * st + 3]);
      u32x4 pw;
      pw.x = hi ? w2 : c[4 * st + 0];
      pw.y = hi ? w3 : c[4 * st + 1];
      pw.z = hi ? c[4 * st + 2] : w0;
      pw.w = hi ? c[4 * st + 3] : w1;
      union { u32x4 u; bf16x8 bf; } pc;
      pc.u = pw;
#pragma unroll
      for (int dt = 0; dt < 4; ++dt) {
        int d = 32 * dt + l31;
        bf16x8 vf = *(const bf16x8*)&Vb[d * 64 + (((2 * st + h) ^ (d & 7)) * 8)];
        oacc[dt] = __builtin_amdgcn_mfma_f32_32x32x16_bf16(vf, pc.bf, oacc[dt], 0, 0, 0);
      }
    }
    __syncthreads();
    cur ^= 1;
  }

  // ---- epilogue: O^T (lane q = l31, d spread over regs) -> LDS [256 q][136 d] -> coalesced store
  u16* Os = smem;
  const float inv = 1.0f / lrun;
  const int q = wid * 32 + l31;
#pragma unroll
  for (int dt = 0; dt < 4; ++dt)
#pragma unroll
    for (int a = 0; a < 4; ++a) {
      int d = 32 * dt + 8 * a + 4 * h;
      ushort4 w;
      w.x = f2bf(oacc[dt][4 * a + 0] * inv);
      w.y = f2bf(oacc[dt][4 * a + 1] * inv);
      w.z = f2bf(oacc[dt][4 * a + 2] * inv);
      w.w = f2bf(oacc[dt][4 * a + 3] * inv);
      *(ushort4*)&Os[q * 136 + d] = w;
    }
  __syncthreads();
  const size_t orow = (size_t)b * 2048 + qt * 256;
#pragma unroll
  for (int rep = 0; rep < 8; ++rep) {
    int idx = rep * 512 + tid;
    int qq = idx >> 4, g = idx & 15;
    us8 v = *(const us8*)&Os[qq * 136 + g * 8];
    *(us8*)&AO[(orow + qq) * 2048 + hd * 128 + g * 8] = v;
  }
#undef STAGE_KV
}

// ---------------------------------------------------------------------------
extern "C" void kernel_launch(void* const* d_in, const int* in_sizes, int n_in,
                              void* d_out, int out_size, void* d_ws, size_t ws_size,
                              hipStream_t stream) {
  const float* x  = (const float*)d_in[0];
  const float* fc = (const float*)d_in[1];
  const float* Wq = (const float*)d_in[2];
  const float* Wk = (const float*)d_in[3];
  const float* Wv = (const float*)d_in[4];
  const float* Wo = (const float*)d_in[5];
  const int* mid  = (const int*)d_in[6];
  float* out = (float*)d_out;
  char* ws = (char*)d_ws;

  // ws layout (bytes)
  u16* XBF = (u16*)(ws);                 // 4096x2048 bf16        16.8MB
  u16* WCT = (u16*)(ws + 16777216);      // 6144x2048 bf16        25.2MB
  u16* WOT = (u16*)(ws + 41943040);      // 4096x2048 bf16        16.8MB
  u16* QKV = (u16*)(ws + 58720256);      // 4096x6144 bf16        50.3MB
  u16* QR  = (u16*)(ws + 109051904);     // [2][16][2048][128]    16.8MB
  u16* KR  = (u16*)(ws + 125829120);     // [2][4][2048][128]      4.2MB
  u16* VT  = (u16*)(ws + 130023424);     // [2][4][128][2048]      4.2MB
  u16* AO  = (u16*)(ws + 134217728);     // [4096][2048]          16.8MB
  if (ws_size < 150994944) return;       // loud failure if scratch too small

  wprep<<<dim3(64, 64, 8), dim3(256), 0, stream>>>(Wq, Wk, Wv, Wo, WCT, WOT);
  xcast<<<dim3(4096), dim3(256), 0, stream>>>(x, XBF);
  gemm_bt<<<dim3(48, 32), dim3(256), 0, stream>>>(XBF, WCT, QKV, 4096, 6144, 2048);
  rope_select<<<dim3(4096), dim3(256), 0, stream>>>(QKV, mid, fc, QR, KR);
  vtrans<<<dim3(64, 16, 2), dim3(256), 0, stream>>>(QKV, mid, VT);
  attn<<<dim3(8, 16, 2), dim3(512), 0, stream>>>(QR, KR, VT, AO);
  gemm_out<<<dim3(32, 32), dim3(256), 0, stream>>>(AO, WOT, mid, out);
}